// Round 9
// baseline (379.539 us; speedup 1.0000x reference)
//
#include <hip/hip_runtime.h>
#include <cstdint>
#include <cstddef>

typedef _Float16 f16;
typedef _Float16 f16x8 __attribute__((ext_vector_type(8)));
typedef float f32x4 __attribute__((ext_vector_type(4)));

#define NB_TOT   2048
#define F0_      39
#define DDIM     32
#define HROW     104            // padded hidden row (f16), 208B, 16B-aligned rows
#define HBATCH   (DDIM*HROW)    // 3328 f16 per batch
// slab: [step32][mt(13)][lane(64)][j(8)] f16 -> 6656 f16 = 13312 B per K32 step
#define SLAB_F16S 6656
#define SLAB_BYTES 13312

// workspace layout (bytes); step counts padded EVEN (pad steps are all-zero: m=39)
#define SZ_H     ((size_t)NB_TOT*HBATCH*2)
#define OFF_H0   ((size_t)0)
#define OFF_H1   (OFF_H0 + SZ_H)
#define OFF_H2   (OFF_H1 + SZ_H)
#define OFF_W0   (OFF_H2 + SZ_H)
#define SZ_W0    ((size_t)50*SLAB_BYTES)
#define OFF_W1   (OFF_W0 + SZ_W0)
#define SZ_W12   ((size_t)128*SLAB_BYTES)
#define OFF_W2   (OFF_W1 + SZ_W12)
#define OFF_BIAS (OFF_W2 + SZ_W12)

// ---------------- prep kernels ----------------

// h0[b][d][n] = (n<39) ? x[b][n][d] : 0   (fp16, transposed, zero-padded)
__global__ void k_prep_h0(const float* __restrict__ x, f16* __restrict__ h0) {
    long idx = (long)blockIdx.x * 256 + threadIdx.x;
    if (idx >= (long)NB_TOT * HBATCH) return;
    int n = (int)(idx % HROW);
    long t = idx / HROW;
    int d = (int)(t % DDIM);
    long b = t / DDIM;
    float v = 0.f;
    if (n < F0_) v = x[(b * F0_ + n) * DDIM + d];
    h0[idx] = (f16)v;
}

// slab[step][mt(13)][lane][j] = W[m*hn+n][o]   (m-major k-order, linear layout)
//   lane = quad*16+d0; o = mt*16+d0; r = step*4+quad; m = r/runs; n = (r%runs)*8+j
// zeros where o>=200 | m>=39 | n>=hn  (pad steps have m>=39 everywhere -> zero)
__global__ void k_prep_w(const float* __restrict__ W, f16* __restrict__ slab,
                         int nsteps, int runs, int hn) {
    long idx = (long)blockIdx.x * 256 + threadIdx.x;
    if (idx >= (long)nsteps * SLAB_F16S) return;
    int e = (int)(idx % SLAB_F16S);
    int step = (int)(idx / SLAB_F16S);
    int j = e & 7;
    int lane = (e >> 3) & 63;
    int mt = e >> 9;
    int quad = lane >> 4, d0 = lane & 15;
    int o = mt * 16 + d0;
    int r = step * 4 + quad;
    int m = r / runs;
    int n = (r - m * runs) * 8 + j;
    float v = 0.f;
    if (o < 200 && m < F0_ && n < hn)
        v = W[((long)m * hn + n) * 200 + o];
    slab[idx] = (f16)v;
}

__global__ void k_prep_bias(const float* __restrict__ b0, const float* __restrict__ b1,
                            const float* __restrict__ b2, float* __restrict__ dst) {
    int idx = blockIdx.x * 256 + threadIdx.x;
    if (idx >= 3 * 208) return;
    int L = idx / 208, o = idx % 208;
    const float* s = (L == 0) ? b0 : (L == 1 ? b1 : b2);
    dst[idx] = (o < 200) ? s[o] : 0.f;
}

// ---------------- main layer kernel ----------------

__device__ __forceinline__ void gl_lds16(const void* g, void* l) {
    __builtin_amdgcn_global_load_lds(
        (const __attribute__((address_space(1))) unsigned int*)g,
        (__attribute__((address_space(3))) unsigned int*)l,
        16, 0, 0);
}

// stage TWO consecutive K32 slabs (one K64 buffer) = 1664 x 16B chunks; 512 threads
__device__ __forceinline__ void stage2(const f16* __restrict__ g, f16* l, int tid) {
#pragma unroll
    for (int rr = 0; rr < 3; ++rr) {
        int c = rr * 512 + tid;
        gl_lds16((const char*)g + (size_t)c * 16, (char*)l + (size_t)c * 16);
    }
    if (tid < 128) {
        int c = 1536 + tid;
        gl_lds16((const char*)g + (size_t)c * 16, (char*)l + (size_t)c * 16);
    }
}

// ONE fat block per CU: 512 thr = 8 waves = (M-half mh x batch-quad bq), 8 batches.
// K64 steps (2 x K32 sub-steps per barrier), double-buffered ring. Stage traffic
// amortized over 8 batches; barrier count halved. R8's proven wave body.
template <int RUNS>
__global__ __launch_bounds__(512, 2) void k_layer(
    const f16* __restrict__ xg,     // transposed x (= h0 buffer), [2048][32][104]
    const f16* __restrict__ hg,     // hidden input, same layout
    const f16* __restrict__ slabg,  // [2*ns64][6656] f16, linear layout
    const float* __restrict__ biasg,// [208], zero-padded
    f16* __restrict__ houtg,        // next hidden (or nullptr)
    float* __restrict__ outg,       // d_out [2048][400]
    int ns64, int direct_lo, int outbase) {
    __shared__ __align__(16) f16 ring[2][2 * SLAB_F16S];   // 53248 B
    __shared__ __align__(16) f16 hl[8][HBATCH];            // 53248 B (106496 total)

    const int tid = threadIdx.x;
    const int w = tid >> 6;
    const int lane = tid & 63;
    const int bq = w & 3;            // batch-pair index within block
    const int mh = w >> 2;           // M-half
    const int bblk = blockIdx.x * 8;
    const int b0i = bblk + bq * 2;
    const int quad = lane >> 4;
    const int d0 = lane & 15;
    const int mtbase = mh * 7;       // 0 or 7
    const int nmt = mh ? 6 : 7;      // 7 + 6 = 13 tiles

    // stage hidden: wave w copies batch w (coalesced u32 copy)
    {
        const unsigned int* src = (const unsigned int*)(hg + (size_t)(bblk + w) * HBATCH);
        unsigned int* dst = (unsigned int*)&hl[w][0];
        for (int i = lane; i < HBATCH / 2; i += 64) dst[i] = src[i];
    }
    stage2(slabg, &ring[0][0], tid);   // K32 slabs 0,1

    f32x4 acc[7][2][2];              // [mt][d-half][batch] -> acc file (112)
#pragma unroll
    for (int mt = 0; mt < 7; ++mt)
#pragma unroll
        for (int nt = 0; nt < 2; ++nt)
#pragma unroll
            for (int bb = 0; bb < 2; ++bb)
                acc[mt][nt][bb] = (f32x4)0.f;

    const f16* xrow0 = xg + (size_t)(b0i + 0) * HBATCH;
    const f16* xrow1 = xg + (size_t)(b0i + 1) * HBATCH;
    const f16* hl0 = &hl[bq * 2 + 0][0];
    const f16* hl1 = &hl[bq * 2 + 1][0];

    // x scalars for step64 0: sub0 (r=quad), sub1 (r=quad+4)  [transient]
    int r0 = quad;
    int m0 = r0 / RUNS;  int nb0 = (r0 - m0 * RUNS) * 8;
    int r1 = quad + 4;
    int m1 = r1 / RUNS;  int nb1 = (r1 - m1 * RUNS) * 8;
    f16 xa0_0 = xrow0[d0 * HROW + m0], xb0_0 = xrow0[(d0 + 16) * HROW + m0];
    f16 xa1_0 = xrow1[d0 * HROW + m0], xb1_0 = xrow1[(d0 + 16) * HROW + m0];
    f16 xa0_1 = xrow0[d0 * HROW + m1], xb0_1 = xrow0[(d0 + 16) * HROW + m1];
    f16 xa1_1 = xrow1[d0 * HROW + m1], xb1_1 = xrow1[(d0 + 16) * HROW + m1];

    __syncthreads();   // hl staged + ring[0] landed

    for (int s = 0; s < ns64; ++s) {
        const int buf = s & 1;
        const bool more = (s + 1 < ns64);
        if (more) stage2(slabg + (size_t)(2 * s + 2) * SLAB_F16S,
                         &ring[buf ^ 1][0], tid);

        // prefetch next step64's x scalars (latency hidden under this step's MFMAs)
        int r0n = r0 + 8, r1n = r1 + 8;
        int m0n = r0n / RUNS, m1n = r1n / RUNS;
        int nb0n = (r0n - m0n * RUNS) * 8, nb1n = (r1n - m1n * RUNS) * 8;
        f16 pa0_0 = (f16)0.f, pb0_0 = (f16)0.f, pa1_0 = (f16)0.f, pb1_0 = (f16)0.f;
        f16 pa0_1 = (f16)0.f, pb0_1 = (f16)0.f, pa1_1 = (f16)0.f, pb1_1 = (f16)0.f;
        if (more) {
            pa0_0 = xrow0[d0 * HROW + m0n];  pb0_0 = xrow0[(d0 + 16) * HROW + m0n];
            pa1_0 = xrow1[d0 * HROW + m0n];  pb1_0 = xrow1[(d0 + 16) * HROW + m0n];
            pa0_1 = xrow0[d0 * HROW + m1n];  pb0_1 = xrow0[(d0 + 16) * HROW + m1n];
            pa1_1 = xrow1[d0 * HROW + m1n];  pb1_1 = xrow1[(d0 + 16) * HROW + m1n];
        }

        // ---- sub-step 0 (K32) ----
        {
            f16x8 h00 = *(const f16x8*)&hl0[d0 * HROW + nb0];
            f16x8 h01 = *(const f16x8*)&hl0[(d0 + 16) * HROW + nb0];
            f16x8 h10 = *(const f16x8*)&hl1[d0 * HROW + nb0];
            f16x8 h11 = *(const f16x8*)&hl1[(d0 + 16) * HROW + nb0];
            f16x8 b00 = h00 * xa0_0;
            f16x8 b01 = h01 * xb0_0;
            f16x8 b10 = h10 * xa1_0;
            f16x8 b11 = h11 * xb1_0;
            const f16* abase = &ring[buf][(size_t)mtbase * 512 + lane * 8];
#pragma unroll
            for (int mt = 0; mt < 7; ++mt) {
                if (mt < nmt) {
                    f16x8 a = *(const f16x8*)(abase + mt * 512);   // linear: 0 conflicts
                    acc[mt][0][0] = __builtin_amdgcn_mfma_f32_16x16x32_f16(a, b00, acc[mt][0][0], 0, 0, 0);
                    acc[mt][1][0] = __builtin_amdgcn_mfma_f32_16x16x32_f16(a, b01, acc[mt][1][0], 0, 0, 0);
                    acc[mt][0][1] = __builtin_amdgcn_mfma_f32_16x16x32_f16(a, b10, acc[mt][0][1], 0, 0, 0);
                    acc[mt][1][1] = __builtin_amdgcn_mfma_f32_16x16x32_f16(a, b11, acc[mt][1][1], 0, 0, 0);
                }
            }
        }
        // ---- sub-step 1 (K32) ----
        {
            f16x8 h00 = *(const f16x8*)&hl0[d0 * HROW + nb1];
            f16x8 h01 = *(const f16x8*)&hl0[(d0 + 16) * HROW + nb1];
            f16x8 h10 = *(const f16x8*)&hl1[d0 * HROW + nb1];
            f16x8 h11 = *(const f16x8*)&hl1[(d0 + 16) * HROW + nb1];
            f16x8 b00 = h00 * xa0_1;
            f16x8 b01 = h01 * xb0_1;
            f16x8 b10 = h10 * xa1_1;
            f16x8 b11 = h11 * xb1_1;
            const f16* abase = &ring[buf][(size_t)SLAB_F16S + mtbase * 512 + lane * 8];
#pragma unroll
            for (int mt = 0; mt < 7; ++mt) {
                if (mt < nmt) {
                    f16x8 a = *(const f16x8*)(abase + mt * 512);
                    acc[mt][0][0] = __builtin_amdgcn_mfma_f32_16x16x32_f16(a, b00, acc[mt][0][0], 0, 0, 0);
                    acc[mt][1][0] = __builtin_amdgcn_mfma_f32_16x16x32_f16(a, b01, acc[mt][1][0], 0, 0, 0);
                    acc[mt][0][1] = __builtin_amdgcn_mfma_f32_16x16x32_f16(a, b10, acc[mt][0][1], 0, 0, 0);
                    acc[mt][1][1] = __builtin_amdgcn_mfma_f32_16x16x32_f16(a, b11, acc[mt][1][1], 0, 0, 0);
                }
            }
        }

        r0 = r0n; r1 = r1n; nb0 = nb0n; nb1 = nb1n;
        xa0_0 = pa0_0; xb0_0 = pb0_0; xa1_0 = pa1_0; xb1_0 = pb1_0;
        xa0_1 = pa0_1; xb0_1 = pb0_1; xa1_1 = pa1_1; xb1_1 = pb1_1;
        __syncthreads();   // ring[buf^1] landed; all reads of ring[buf] done
    }

    // -------- epilogue (ring becomes scratch: 26624 f16 = exactly 8 x HBATCH) --------
    const bool wrh = (houtg != nullptr);
    f16* sc = ((f16*)ring) + (size_t)bq * (2 * HBATCH);   // this pair's 2-batch scratch
    if (wrh && mh == 0) {            // hidden rows o<100 all live in M-half 0
        unsigned int* sz = (unsigned int*)sc;
        for (int i = lane; i < HBATCH; i += 64) sz[i] = 0u;   // zero 2*HBATCH f16
    }

#pragma unroll
    for (int mt = 0; mt < 7; ++mt) {
        if (mt < nmt) {
#pragma unroll
            for (int bb = 0; bb < 2; ++bb) {
                float v[2][4];
#pragma unroll
                for (int nt = 0; nt < 2; ++nt)
#pragma unroll
                    for (int i = 0; i < 4; ++i) {
                        int o = (mtbase + mt) * 16 + quad * 4 + i;
                        float t = acc[mt][nt][bb][i] + biasg[o];
                        v[nt][i] = t > 0.f ? t : 0.f;
                    }
                if (wrh && mh == 0) {
#pragma unroll
                    for (int nt = 0; nt < 2; ++nt)
#pragma unroll
                        for (int i = 0; i < 4; ++i) {
                            int o = mt * 16 + quad * 4 + i;
                            if (o < 100)
                                sc[bb * HBATCH + (d0 + 16 * nt) * HROW + o] = (f16)v[nt][i];
                        }
                }
                float s2[4];
#pragma unroll
                for (int i = 0; i < 4; ++i) s2[i] = v[0][i] + v[1][i];
#pragma unroll
                for (int mask = 1; mask <= 8; mask <<= 1)
#pragma unroll
                    for (int i = 0; i < 4; ++i) s2[i] += __shfl_xor(s2[i], mask, 64);
                if (d0 == 0) {
#pragma unroll
                    for (int i = 0; i < 4; ++i) {
                        int o = (mtbase + mt) * 16 + quad * 4 + i;
                        if (o >= direct_lo && o < 200)
                            outg[(size_t)(b0i + bb) * 400 + outbase + (o - direct_lo)] = s2[i];
                    }
                }
            }
        }
    }

    if (wrh) {
        __syncthreads();   // all mh==0 scratch writes visible
        // wave w copies batch w's transposed hidden back to global (coalesced u32)
        const unsigned int* s3 = (const unsigned int*)(((f16*)ring) + (size_t)w * HBATCH);
        unsigned int* dg = (unsigned int*)(houtg + (size_t)(bblk + w) * HBATCH);
        for (int i = lane; i < HBATCH / 2; i += 64) dg[i] = s3[i];
    }
}

// ---------------- launch ----------------

extern "C" void kernel_launch(void* const* d_in, const int* in_sizes, int n_in,
                              void* d_out, int out_size, void* d_ws, size_t ws_size,
                              hipStream_t stream) {
    const float* x  = (const float*)d_in[0];
    const float* W0 = (const float*)d_in[1];
    const float* b0 = (const float*)d_in[2];
    const float* W1 = (const float*)d_in[3];
    const float* b1 = (const float*)d_in[4];
    const float* W2 = (const float*)d_in[5];
    const float* b2 = (const float*)d_in[6];
    float* out = (float*)d_out;
    char* ws = (char*)d_ws;

    f16* h0 = (f16*)(ws + OFF_H0);
    f16* h1 = (f16*)(ws + OFF_H1);
    f16* h2 = (f16*)(ws + OFF_H2);
    f16* w0s = (f16*)(ws + OFF_W0);
    f16* w1s = (f16*)(ws + OFF_W1);
    f16* w2s = (f16*)(ws + OFF_W2);
    float* biasws = (float*)(ws + OFF_BIAS);

    {
        long tot = (long)NB_TOT * HBATCH;
        k_prep_h0<<<(unsigned)((tot + 255) / 256), 256, 0, stream>>>(x, h0);
    }
    // padded to even step counts: 50 and 128 (pad steps all-zero via m>=39)
    k_prep_w<<<(unsigned)(((long)50 * SLAB_F16S + 255) / 256), 256, 0, stream>>>(W0, w0s, 50, 5, 39);
    k_prep_w<<<(unsigned)(((long)128 * SLAB_F16S + 255) / 256), 256, 0, stream>>>(W1, w1s, 128, 13, 100);
    k_prep_w<<<(unsigned)(((long)128 * SLAB_F16S + 255) / 256), 256, 0, stream>>>(W2, w2s, 128, 13, 100);
    k_prep_bias<<<3, 256, 0, stream>>>(b0, b1, b2, biasws);

    // layer 0: hidden=x (hn=39, RUNS=5, 25 K64-steps); direct = cur[100:200] -> out[:,0:100)
    k_layer<5><<<256, 512, 0, stream>>>(h0, h0, w0s, biasws + 0, h1, out, 25, 100, 0);
    // layer 1: hn=100, RUNS=13, 64 K64-steps; direct = cur[100:200] -> out[:,100:200)
    k_layer<13><<<256, 512, 0, stream>>>(h0, h1, w1s, biasws + 208, h2, out, 64, 100, 100);
    // layer 2: hn=100, RUNS=13, 64 K64-steps; direct = full cur -> out[:,200:400)
    k_layer<13><<<256, 512, 0, stream>>>(h0, h2, w2s, biasws + 416, (f16*)nullptr, out, 64, 0, 200);
}